// Round 19
// baseline (333.159 us; speedup 1.0000x reference)
//
#include <hip/hip_runtime.h>
#include <math.h>

#define NR 131072
#define KC 1024
#define DD 256

// d_out element offsets (float32 elements)
#define ZQ_OFF  0
#define RES_OFF 33554432
#define IDX_OFF 67108864
#define LOSS_OFF 67239936
#define PERP_OFF 67239937

// ws byte offsets (total ~1.06 MB)
#define WS_CNT 0          // int[1024]
#define WS_C2N 4096       // float[1024]
#define WS_IDX 8192       // int[131072] = 512KB
#define WS_BSS 532480     // double[2048]
#define WS_CBS 548864     // ushort cbs hi-only: 64 tiles x 8KB = 512KB

#define MARG 5e-4f
#define CCAP 24

#define FM(x,y) __fmul_rn((x),(y))
#define FA(x,y) __fadd_rn((x),(y))

typedef __attribute__((ext_vector_type(8))) short bf16x8;
typedef __attribute__((ext_vector_type(4))) float f32x4;

static __device__ __forceinline__ unsigned short bf16h(float f) {
  unsigned int u = __float_as_uint(f);
  u += 0x7FFFu + ((u >> 16) & 1u);
  return (unsigned short)(u >> 16);
}

// ---- numpy f32 pairwise sum-of-squares, one 128-block (AVX512 tree) --------
static __device__ __forceinline__ float np_sumsq128(const float* __restrict__ q) {
  float lane[16];
#pragma unroll
  for (int l = 0; l < 16; l++) {
    float s0 = FM(q[l +   0], q[l +   0]);
    float s1 = FM(q[l +  16], q[l +  16]);
    float s2 = FM(q[l +  32], q[l +  32]);
    float s3 = FM(q[l +  48], q[l +  48]);
    float s4 = FM(q[l +  64], q[l +  64]);
    float s5 = FM(q[l +  80], q[l +  80]);
    float s6 = FM(q[l +  96], q[l +  96]);
    float s7 = FM(q[l + 112], q[l + 112]);
    lane[l] = FA(FA(FA(s0, s1), FA(s2, s3)), FA(FA(s4, s5), FA(s6, s7)));
  }
#pragma unroll
  for (int h = 8; h >= 1; h >>= 1)
#pragma unroll
    for (int l = 0; l < 8; l++)
      if (l < h) lane[l] = FA(lane[l], lane[l + h]);
  return lane[0];
}

static __device__ __forceinline__ float np_sumsq256(const float* __restrict__ p) {
  return FA(np_sumsq128(p), np_sumsq128(p + 128));
}

// ---------------- K1a: codebook c2 (numpy-replica f32) ----------------------
__global__ void vqt_c2(const float* __restrict__ cb, float* __restrict__ c2n) {
  const int code = blockIdx.x * 256 + threadIdx.x;
  if (code < KC) c2n[code] = np_sumsq256(cb + (size_t)code * DD);
}

// ---------------- K1b: codebook bf16 hi split, MFMA-granule layout ----------
__global__ void vqt_cbsplit(const float* __restrict__ cb,
                            unsigned short* __restrict__ cbs) {
  const int g  = blockIdx.x * 256 + threadIdx.x;   // 0..32767
  const int t  = g >> 9;
  const int gi = g & 511;
  const int kc = gi >> 6, q = (gi >> 4) & 3, c = gi & 15;
  const float* src = cb + (size_t)(t * 16 + c) * DD + kc * 32 + q * 8;
  unsigned int w[4];
#pragma unroll
  for (int p = 0; p < 4; p++)
    w[p] = (unsigned int)bf16h(src[p * 2]) |
           ((unsigned int)bf16h(src[p * 2 + 1]) << 16);
  *(uint4*)(cbs + (size_t)g * 8) = make_uint4(w[0], w[1], w[2], w[3]);
}

// ---------------- K2: screen + finalize ONLY (no epilogue) ------------------
// r18's proven kernel minus output streaming: wave-decoupled, barrier-free.
// Writes idx (int) to ws for the streaming epilogue kernel + float idx to out.
__global__ __launch_bounds__(256, 4) void vqt_main(
    const float* __restrict__ z, const float* __restrict__ cb,
    const unsigned short* __restrict__ cbs,
    const float* __restrict__ c2n,
    float* __restrict__ out, int* __restrict__ counts,
    int* __restrict__ idxw) {
  __shared__ unsigned short ccode[128][CCAP];           //  6 KB
  __shared__ float cd[128][CCAP];                       // 12 KB
  __shared__ int ccnt[128];
  __shared__ float m1row[128];
  __shared__ float z2s[128];
  __shared__ __align__(16) float c2l[1024];             //  4 KB

  const int tid = threadIdx.x, wg = blockIdx.x;
  const int wv = tid >> 6, ln = tid & 63;
  const int rl = ln & 15;           // row within group
  const int qk = ln >> 4;           // k-octet / code-quad selector
  const int rowg0 = wg * 128 + wv * 32 + rl;      // group-0 global row

  // ---- c2 into LDS: every wave loads ALL of it (benign same-value race) ----
#pragma unroll
  for (int i = 0; i < 4; i++)
    ((float4*)c2l)[i * 64 + ln] = ((const float4*)c2n)[i * 64 + ln];
  // ---- per-wave candidate-count init ----
  if (ln < 32) ccnt[wv * 32 + ln] = 0;

  // ---- build z hi-fragments in registers for both row-groups ----
  bf16x8 zH0[8], zH1[8];
#pragma unroll
  for (int kc = 0; kc < 8; kc++) {
    const float4* p0 = (const float4*)(z + (size_t)rowg0 * DD + kc * 32 + qk * 8);
    const float4* p1 = (const float4*)(z + (size_t)(rowg0 + 16) * DD + kc * 32 + qk * 8);
    const float4 a0 = p0[0], b0 = p0[1];
    const float4 a1 = p1[0], b1 = p1[1];
    zH0[kc][0] = (short)bf16h(a0.x); zH0[kc][1] = (short)bf16h(a0.y);
    zH0[kc][2] = (short)bf16h(a0.z); zH0[kc][3] = (short)bf16h(a0.w);
    zH0[kc][4] = (short)bf16h(b0.x); zH0[kc][5] = (short)bf16h(b0.y);
    zH0[kc][6] = (short)bf16h(b0.z); zH0[kc][7] = (short)bf16h(b0.w);
    zH1[kc][0] = (short)bf16h(a1.x); zH1[kc][1] = (short)bf16h(a1.y);
    zH1[kc][2] = (short)bf16h(a1.z); zH1[kc][3] = (short)bf16h(a1.w);
    zH1[kc][4] = (short)bf16h(b1.x); zH1[kc][5] = (short)bf16h(b1.y);
    zH1[kc][6] = (short)bf16h(b1.z); zH1[kc][7] = (short)bf16h(b1.w);
  }

  // ---- z2 (exact np AVX512 tree), wave-own rows only ----
  {
    const int gg = ln >> 4, l = ln & 15;
#pragma unroll 1
    for (int g4 = 0; g4 < 8; g4++) {
      const int rlcl = wv * 32 + g4 * 4 + gg;
      const float* q = z + (size_t)(wg * 128 + rlcl) * DD;
      float blk[2];
#pragma unroll
      for (int b = 0; b < 2; b++) {
        const float* qq = q + b * 128;
        const float s0 = FM(qq[l +   0], qq[l +   0]);
        const float s1 = FM(qq[l +  16], qq[l +  16]);
        const float s2 = FM(qq[l +  32], qq[l +  32]);
        const float s3 = FM(qq[l +  48], qq[l +  48]);
        const float s4 = FM(qq[l +  64], qq[l +  64]);
        const float s5 = FM(qq[l +  80], qq[l +  80]);
        const float s6 = FM(qq[l +  96], qq[l +  96]);
        const float s7 = FM(qq[l + 112], qq[l + 112]);
        float v = FA(FA(FA(s0, s1), FA(s2, s3)), FA(FA(s4, s5), FA(s6, s7)));
#pragma unroll
        for (int h = 8; h >= 1; h >>= 1) v = FA(v, __shfl_down(v, h, 16));
        blk[b] = v;
      }
      if (l == 0) z2s[rlcl] = FA(blk[0], blk[1]);
    }
  }

  const float z2v0 = z2s[wv * 32 + rl];
  const float z2v1 = z2s[wv * 32 + rl + 16];
  const int rw0 = wv * 32 + rl;

  float m10 = INFINITY, m11 = INFINITY;
#pragma unroll 2
  for (int t = 0; t < 64; t++) {
    // direct global->register A-fragments (L2-resident cbs, coalesced 1KB/load)
    bf16x8 aH[8];
#pragma unroll
    for (int kc = 0; kc < 8; kc++)
      aH[kc] = *(const bf16x8*)(cbs + (size_t)t * 4096 + kc * 512 + ln * 8);

    f32x4 accA = {0.f, 0.f, 0.f, 0.f}, accB = accA;
#pragma unroll
    for (int kc = 0; kc < 8; kc++) {
      accA = __builtin_amdgcn_mfma_f32_16x16x32_bf16(aH[kc], zH0[kc], accA, 0, 0, 0);
      accB = __builtin_amdgcn_mfma_f32_16x16x32_bf16(aH[kc], zH1[kc], accB, 0, 0, 0);
    }
    // fold: lane covers codes t*16 + qk*4 + r, rows (group0, group1)
    const float4 c2v4 = *(const float4*)&c2l[t * 16 + qk * 4];
    float dh0[4], dh1[4];
#pragma unroll
    for (int r = 0; r < 4; r++) {
      const float c2v = r == 0 ? c2v4.x : r == 1 ? c2v4.y : r == 2 ? c2v4.z : c2v4.w;
      dh0[r] = z2v0 - 2.f * accA[r] + c2v;
      dh1[r] = z2v1 - 2.f * accB[r] + c2v;
      m10 = fminf(m10, dh0[r]);
      m11 = fminf(m11, dh1[r]);
    }
    m10 = fminf(m10, __shfl_xor(m10, 16));
    m10 = fminf(m10, __shfl_xor(m10, 32));
    m11 = fminf(m11, __shfl_xor(m11, 16));
    m11 = fminf(m11, __shfl_xor(m11, 32));
#pragma unroll
    for (int r = 0; r < 4; r++) {
      if (dh0[r] <= m10 + MARG) {
        const int s = atomicAdd(&ccnt[rw0], 1);
        if (s < CCAP) {
          ccode[rw0][s] = (unsigned short)(t * 16 + qk * 4 + r);
          cd[rw0][s] = dh0[r];
        }
      }
      if (dh1[r] <= m11 + MARG) {
        const int s = atomicAdd(&ccnt[rw0 + 16], 1);
        if (s < CCAP) {
          ccode[rw0 + 16][s] = (unsigned short)(t * 16 + qk * 4 + r);
          cd[rw0 + 16][s] = dh1[r];
        }
      }
    }
  }

  if (qk == 0) { m1row[rw0] = m10; m1row[rw0 + 16] = m11; }
  // (no barrier: all state is wave-own)

  // ---- finalize (wave-own rows: lanes 0..31 -> rows wv*32+ln) ----
  if (ln < 32) {
    const int rwl = wv * 32 + ln;
    const int row = wg * 128 + rwl;
    const float mf = m1row[rwl] + MARG;
    const int nc = ccnt[rwl];
    int best;
    if (nc > CCAP) {             // overflow (P~0): full exact np scan
      const float* zr = z + (size_t)row * DD;
      const float z2r = z2s[rwl];
      float db = INFINITY; best = 0;
      for (int c = 0; c < KC; c++) {
        const float* cr = cb + (size_t)c * DD;
        float dot = 0.f;
#pragma unroll 8
        for (int k = 0; k < DD; k++) dot = __fmaf_rn(zr[k], cr[k], dot);
        const float t1 = 2.0f * dot;
        const float d = FA(FA(z2r, -t1), c2l[c]);
        if (d < db) { db = d; best = c; }          // ascending c: first-min
      }
    } else {
      int kept = 0, kcode = 0;
      for (int s = 0; s < nc; s++)
        if (cd[rwl][s] <= mf) { kept++; kcode = ccode[rwl][s]; }
      if (kept == 1) best = kcode;
      else {
        const float* zr = z + (size_t)row * DD;
        const float z2r = z2s[rwl];
        float db = INFINITY; int bi = 0x7FFFFFFF;
        for (int s = 0; s < nc; s++) {
          if (cd[rwl][s] > mf) continue;
          const int c = ccode[rwl][s];
          const float* cr = cb + (size_t)c * DD;
          float dot = 0.f;
#pragma unroll 8
          for (int k = 0; k < DD; k++) dot = __fmaf_rn(zr[k], cr[k], dot);
          const float t1 = 2.0f * dot;
          const float d = FA(FA(z2r, -t1), c2l[c]);   // exact np-f32 d
          if (d < db || (d == db && c < bi)) { db = d; bi = c; }
        }
        best = bi;
      }
    }
    atomicAdd(&counts[best], 1);
    idxw[row] = best;
    out[IDX_OFF + row] = (float)best;
  }
}

// ---------------- K3: streaming epilogue (gather + outputs + loss) ----------
// Pure streaming kernel: 2048 WGs x 4 waves, 16 consecutive rows per wave,
// 8-row batches with 16 independent loads in flight (r17-proven pattern).
// Big grid -> scheduler backfill, no coupling to screen stragglers.
__global__ __launch_bounds__(256) void vqt_out(
    const float* __restrict__ z, const float* __restrict__ cb,
    const int* __restrict__ idxw, float* __restrict__ out,
    double* __restrict__ bss) {
  __shared__ double wred[4];
  const int wv = threadIdx.x >> 6, ln = threadIdx.x & 63;
  const int rowbase = (blockIdx.x * 4 + wv) * 16;

  float ss = 0.f;
#pragma unroll 1
  for (int g = 0; g < 16; g += 8) {
    float4 r4b[8], q4b[8];
#pragma unroll
    for (int u = 0; u < 8; u++) {
      const size_t zrow = (size_t)(rowbase + g + u) * DD;
      r4b[u] = ((const float4*)(z + zrow))[ln];
      q4b[u] = ((const float4*)(cb + (size_t)idxw[rowbase + g + u] * DD))[ln];
    }
#pragma unroll
    for (int u = 0; u < 8; u++) {
      const size_t zrow = (size_t)(rowbase + g + u) * DD;
      const float4 r4 = r4b[u];
      const float4 q4 = q4b[u];
      float4 stv, rsv; float dq;
      stv.x = r4.x + (q4.x - r4.x); rsv.x = r4.x - q4.x; dq = q4.x - r4.x; ss = fmaf(dq, dq, ss);
      stv.y = r4.y + (q4.y - r4.y); rsv.y = r4.y - q4.y; dq = q4.y - r4.y; ss = fmaf(dq, dq, ss);
      stv.z = r4.z + (q4.z - r4.z); rsv.z = r4.z - q4.z; dq = q4.z - r4.z; ss = fmaf(dq, dq, ss);
      stv.w = r4.w + (q4.w - r4.w); rsv.w = r4.w - q4.w; dq = q4.w - r4.w; ss = fmaf(dq, dq, ss);
      ((float4*)(out + ZQ_OFF  + zrow))[ln] = stv;
      ((float4*)(out + RES_OFF + zrow))[ln] = rsv;
    }
  }
  double dss = (double)ss;
  for (int o = 32; o; o >>= 1) dss += __shfl_down(dss, o, 64);
  if (ln == 0) wred[wv] = dss;
  __syncthreads();
  if (threadIdx.x == 0) bss[blockIdx.x] = wred[0] + wred[1] + wred[2] + wred[3];
}

// ---------------- K4: scalars (loss, perplexity) ----------------------------
__global__ void vqt_final(const int* __restrict__ counts,
                          const double* __restrict__ bss,
                          float* __restrict__ out) {
  __shared__ double red[256];
  const int t = threadIdx.x;
  double s = 0.0;
  for (int i = t; i < 2048; i += 256) s += bss[i];
  red[t] = s; __syncthreads();
  for (int s2 = 128; s2 > 0; s2 >>= 1) { if (t < s2) red[t] += red[t + s2]; __syncthreads(); }
  const double ssq = red[0];
  __syncthreads();
  double h = 0.0;
  for (int c = t; c < 1024; c += 256) {
    double p = (double)counts[c] / 131072.0;
    h += p * log(p + 1e-10);
  }
  red[t] = h; __syncthreads();
  for (int s2 = 128; s2 > 0; s2 >>= 1) { if (t < s2) red[t] += red[t + s2]; __syncthreads(); }
  if (t == 0) {
    out[LOSS_OFF] = (float)(0.25 * ssq / 33554432.0);
    out[PERP_OFF] = (float)exp(-red[0]);
  }
}

extern "C" void kernel_launch(void* const* d_in, const int* in_sizes, int n_in,
                              void* d_out, int out_size, void* d_ws, size_t ws_size,
                              hipStream_t stream) {
  // Bind inputs by SIZE: z has 33,554,432 elems, codebook 262,144.
  const float* z;
  const float* cb;
  if (in_sizes[0] == NR * DD) { z = (const float*)d_in[0]; cb = (const float*)d_in[1]; }
  else                        { cb = (const float*)d_in[0]; z = (const float*)d_in[1]; }

  float* out = (float*)d_out;
  char* ws = (char*)d_ws;
  int*            counts = (int*)(ws + WS_CNT);
  float*          c2n    = (float*)(ws + WS_C2N);
  int*            idxw   = (int*)(ws + WS_IDX);
  double*         bssp   = (double*)(ws + WS_BSS);
  unsigned short* cbs    = (unsigned short*)(ws + WS_CBS);

  hipMemsetAsync(counts, 0, 4096, stream);
  vqt_c2<<<4, 256, 0, stream>>>(cb, c2n);
  vqt_cbsplit<<<128, 256, 0, stream>>>(cb, cbs);
  vqt_main<<<NR / 128, 256, 0, stream>>>(z, cb, cbs, c2n, out, counts, idxw);
  vqt_out<<<2048, 256, 0, stream>>>(z, cb, idxw, out, bssp);
  vqt_final<<<1, 256, 0, stream>>>(counts, bssp, out);
}